// Round 8
// baseline (376.428 us; speedup 1.0000x reference)
//
#include <hip/hip_runtime.h>
#include <math.h>

#define Bsz   256
#define Nn    2048
#define Md    64
#define CSd   512
#define INPd  256
#define OUTd  256
#define KTOT  832      // INP + M + CS
#define PSTRIDE 272    // per-batch params: kr[64] kw[64] erase[64] add[64] S[16]
#define GSZ   524288   // 256*2048 gates elements (one split partial)
#define ZSPL  4        // K splits for gates GEMM
#define KZ    208      // K per split = 832/4 = 13*16

__device__ __forceinline__ float sigmoidf_(float x){ return 1.f/(1.f+expf(-x)); }
__device__ __forceinline__ float softplusf_(float x){ return fmaxf(x,0.f) + log1pf(expf(-fabsf(x))); }

__device__ __forceinline__ float4 loadA4(const float* __restrict__ x, const float* __restrict__ pr,
                                         const float* __restrict__ h, int row, int k){
  if (k < INPd)            return *(const float4*)&x[row*INPd + k];
  else if (k < INPd+Md)    return *(const float4*)&pr[row*Md + (k-INPd)];
  else                     return *(const float4*)&h[row*CSd + (k-INPd-Md)];
}
__device__ __forceinline__ float4 loadW4(const float* __restrict__ Wih, const float* __restrict__ Whh,
                                         int j, int k){
  if (k < INPd+Md)         return *(const float4*)&Wih[j*(INPd+Md) + k];
  else                     return *(const float4*)&Whh[j*CSd + (k-INPd-Md)];
}

// ---------------- Kernel 1: gates partials, split-K GEMM
// tile 64x64, BK=16, Z=4 -> 512 blocks (2/CU, 8 waves/CU)
__global__ __launch_bounds__(256) void k_gates(
    const float* __restrict__ x, const float* __restrict__ prev_read, const float* __restrict__ h,
    const float* __restrict__ W_ih, const float* __restrict__ W_hh,
    float* __restrict__ partials)
{
  __shared__ __align__(16) float As[16][68];   // [k][row]
  __shared__ __align__(16) float Bs[16][68];   // [k][col]
  const int t = threadIdx.x;             // 0..255
  const int col0 = blockIdx.x * 64;
  const int row0 = blockIdx.y * 64;
  const int z    = blockIdx.z;
  const int lr = t >> 2;                 // 0..63 staging row/col
  const int kq = (t & 3) * 4;            // k offset within 16-slab
  const int tr = t >> 4, tc = t & 15;    // 16x16 compute grid
  const int arow = row0 + lr;
  const int bcol = col0 + lr;

  float acc[4][4] = {};
  int kb = z * KZ;
  float4 a  = loadA4(x, prev_read, h, arow, kb + kq);
  float4 bq = loadW4(W_ih, W_hh, bcol, kb + kq);

  for (int kc = 0; kc < 13; ++kc) {
    As[kq+0][lr] = a.x;  As[kq+1][lr] = a.y;  As[kq+2][lr] = a.z;  As[kq+3][lr] = a.w;
    Bs[kq+0][lr] = bq.x; Bs[kq+1][lr] = bq.y; Bs[kq+2][lr] = bq.z; Bs[kq+3][lr] = bq.w;
    __syncthreads();
    if (kc < 12) {
      int kn = kb + (kc+1)*16 + kq;
      a  = loadA4(x, prev_read, h, arow, kn);
      bq = loadW4(W_ih, W_hh, bcol, kn);
    }
    #pragma unroll
    for (int kk = 0; kk < 16; ++kk) {
      float av[4], bv[4];
      *(float4*)&av[0] = *(const float4*)&As[kk][tr*4];
      *(float4*)&bv[0] = *(const float4*)&Bs[kk][tc*4];
      #pragma unroll
      for (int i=0;i<4;++i)
        #pragma unroll
        for (int q=0;q<4;++q)
          acc[i][q] += av[i]*bv[q];
    }
    __syncthreads();
  }
  float* part = partials + (size_t)z * GSZ;
  #pragma unroll
  for (int i=0;i<4;++i) {
    int r = row0 + tr*4 + i;
    float4 v0 = {acc[i][0],acc[i][1],acc[i][2],acc[i][3]};
    *(float4*)&part[r*2048 + col0 + tc*4] = v0;
  }
}

// ---------------- Kernel 2: LSTM elementwise + head projections + params
// one block per batch, 512 threads (8 waves)
__global__ __launch_bounds__(512) void k_head(
    const float* __restrict__ partials, const float* __restrict__ c,
    const float* __restrict__ b_ih, const float* __restrict__ b_hh,
    const float* __restrict__ W_r, const float* __restrict__ b_r,
    const float* __restrict__ W_w, const float* __restrict__ b_w,
    float* __restrict__ h_new, float* __restrict__ c_new, float* __restrict__ params)
{
  __shared__ float hs[CSd];
  __shared__ float ob[268];
  int b = blockIdx.x, t = threadIdx.x;
  // --- LSTM: thread t owns element (b, t)
  float g[4];
  #pragma unroll
  for (int q = 0; q < 4; ++q) {
    int col = q*512 + t;
    float s = b_ih[col] + b_hh[col];
    #pragma unroll
    for (int sp = 0; sp < ZSPL; ++sp) s += partials[(size_t)sp*GSZ + b*2048 + col];
    g[q] = s;
  }
  float ig = sigmoidf_(g[0]);
  float fg = sigmoidf_(g[1]);
  float gg = tanhf(g[2]);
  float og = sigmoidf_(g[3]);
  float cn = fg * c[b*CSd + t] + ig * gg;
  float hn = og * tanhf(cn);
  c_new[b*CSd + t] = cn;
  h_new[b*CSd + t] = hn;
  hs[t] = hn;
  __syncthreads();
  // --- heads GEMV: wave-per-row
  int wave = t >> 6, lane = t & 63;
  for (int r = wave; r < 268; r += 8) {
    const float* wrow; float bias;
    if (r < 70) { wrow = W_r + r*CSd;      bias = b_r[r]; }
    else        { wrow = W_w + (r-70)*CSd; bias = b_w[r-70]; }
    float s = 0.f;
    #pragma unroll
    for (int i = 0; i < 8; ++i) s += wrow[i*64 + lane] * hs[i*64 + lane];
    #pragma unroll
    for (int off = 32; off; off >>= 1) s += __shfl_xor(s, off);
    if (lane == 0) ob[r] = s + bias;
  }
  __syncthreads();
  // --- params
  float* P = params + b*PSTRIDE;
  if (t < 256) {
    if (t < 64)       P[t] = ob[t];                           // k_r
    else if (t < 128) P[t] = ob[70 + (t-64)];                 // k_w
    else if (t < 192) P[t] = sigmoidf_(ob[140 + (t-128)]);    // erase
    else              P[t] = ob[204 + (t-192)];               // add
  }
  float* S = P + 256;
  if (wave == 0) {
    float v = ob[lane]; float sq = v*v;
    #pragma unroll
    for (int off = 32; off; off >>= 1) sq += __shfl_xor(sq, off);
    if (lane == 0) S[6] = 1.f/(sqrtf(sq)+1e-8f);
  } else if (wave == 1) {
    float v = ob[70 + lane]; float sq = v*v;
    #pragma unroll
    for (int off = 32; off; off >>= 1) sq += __shfl_xor(sq, off);
    if (lane == 0) S[13] = 1.f/(sqrtf(sq)+1e-8f);
  }
  if (t == 128) {
    S[0] = softplusf_(ob[64]);
    S[1] = sigmoidf_(ob[65]);
    float m3 = fmaxf(ob[66], fmaxf(ob[67], ob[68]));
    float e0=expf(ob[66]-m3), e1=expf(ob[67]-m3), e2=expf(ob[68]-m3);
    float es = e0+e1+e2;
    S[2]=e0/es; S[3]=e1/es; S[4]=e2/es;
    S[5] = 1.f + softplusf_(ob[69]);
  }
  if (t == 129) {
    S[7] = softplusf_(ob[134]);
    S[8] = sigmoidf_(ob[135]);
    float m3 = fmaxf(ob[136], fmaxf(ob[137], ob[138]));
    float e0=expf(ob[136]-m3), e1=expf(ob[137]-m3), e2=expf(ob[138]-m3);
    float es = e0+e1+e2;
    S[9]=e0/es; S[10]=e1/es; S[11]=e2/es;
    S[12] = 1.f + softplusf_(ob[139]);
  }
}

// ---------------- Kernel 3: cosine sim, high-TLP: grid (8,256) = 2048 blocks
// block handles 256 rows; coalesced 16 lanes/row; depth-8 pipeline
__global__ __launch_bounds__(256) void k_sim(
    const float* __restrict__ mem, const float* __restrict__ params,
    float* __restrict__ a_r, float* __restrict__ a_w)
{
  int b = blockIdx.y;
  int n0 = blockIdx.x * 256;
  int t = threadIdx.x;
  int rr = t >> 4, chunk = t & 15;     // 16 rows per pass, 16 passes
  const float* P = params + b*PSTRIDE;
  float4 kr = ((const float4*)P)[chunk];
  float4 kw = ((const float4*)(P+64))[chunk];
  const float* S = P + 256;
  float cr = S[0]*S[6];
  float cw = S[7]*S[13];
  const float4* m4 = (const float4*)mem + ((size_t)b*Nn + n0)*16;
  float* arow = a_r + b*Nn + n0;
  float* awrow = a_w + b*Nn + n0;
  float4 v0,v1,v2,v3,v4,v5,v6,v7;
  v0 = m4[(size_t)(0*16+rr)*16 + chunk];
  v1 = m4[(size_t)(1*16+rr)*16 + chunk];
  v2 = m4[(size_t)(2*16+rr)*16 + chunk];
  v3 = m4[(size_t)(3*16+rr)*16 + chunk];
  v4 = m4[(size_t)(4*16+rr)*16 + chunk];
  v5 = m4[(size_t)(5*16+rr)*16 + chunk];
  v6 = m4[(size_t)(6*16+rr)*16 + chunk];
  v7 = m4[(size_t)(7*16+rr)*16 + chunk];
#define SIMST(V,PP) { \
    float ss = V.x*V.x + V.y*V.y + V.z*V.z + V.w*V.w; \
    float pr = V.x*kr.x + V.y*kr.y + V.z*kr.z + V.w*kr.w; \
    float pw = V.x*kw.x + V.y*kw.y + V.z*kw.z + V.w*kw.w; \
    _Pragma("unroll") \
    for (int off=8; off; off>>=1) { \
      ss += __shfl_xor(ss, off); \
      pr += __shfl_xor(pr, off); \
      pw += __shfl_xor(pw, off); \
    } \
    if (chunk == 0) { \
      int n = (PP)*16 + rr; \
      float inv_nm = 1.f/(sqrtf(ss)+1e-8f); \
      arow[n]  = cr * pr * inv_nm; \
      awrow[n] = cw * pw * inv_nm; \
    } }
  for (int p = 0; p < 16; p += 8) {
    float4 c0=v0,c1=v1,c2=v2,c3=v3,c4=v4,c5=v5,c6=v6,c7=v7;
    if (p + 8 < 16) {
      v0 = m4[(size_t)((p+ 8)*16+rr)*16 + chunk];
      v1 = m4[(size_t)((p+ 9)*16+rr)*16 + chunk];
      v2 = m4[(size_t)((p+10)*16+rr)*16 + chunk];
      v3 = m4[(size_t)((p+11)*16+rr)*16 + chunk];
      v4 = m4[(size_t)((p+12)*16+rr)*16 + chunk];
      v5 = m4[(size_t)((p+13)*16+rr)*16 + chunk];
      v6 = m4[(size_t)((p+14)*16+rr)*16 + chunk];
      v7 = m4[(size_t)((p+15)*16+rr)*16 + chunk];
    }
    SIMST(c0,p)   SIMST(c1,p+1) SIMST(c2,p+2) SIMST(c3,p+3)
    SIMST(c4,p+4) SIMST(c5,p+5) SIMST(c6,p+6) SIMST(c7,p+7)
  }
#undef SIMST
}

// ---------------- Kernel 4: softmax -> interpolate -> shift -> sharpen -> normalize
__device__ __forceinline__ float block_reduce512(float val, float* red, int t, bool ismax){
  #pragma unroll
  for (int off=32; off; off>>=1)
    val = ismax ? fmaxf(val, __shfl_xor(val,off)) : val + __shfl_xor(val,off);
  __syncthreads();
  if ((t&63)==0) red[t>>6] = val;
  __syncthreads();
  float r = red[0];
  if (ismax) { for (int i=1;i<8;++i) r = fmaxf(r, red[i]); }
  else       { for (int i=1;i<8;++i) r += red[i]; }
  return r;
}

__global__ __launch_bounds__(512) void k_weights(
    const float* __restrict__ a_r, const float* __restrict__ a_w,
    const float* __restrict__ read_w, const float* __restrict__ write_w,
    const float* __restrict__ params,
    float* __restrict__ w_read, float* __restrict__ w_write)
{
  __shared__ float wg[Nn];
  __shared__ float red[8];
  int b = blockIdx.x;
  int which = blockIdx.y;
  const float* a    = which ? a_w     : a_r;
  const float* prev = which ? write_w : read_w;
  float* outw       = which ? w_write : w_read;
  const float* S = params + b*PSTRIDE + 256 + (which ? 7 : 0);
  float g = S[1], s0 = S[2], s1 = S[3], s2 = S[4], gamma = S[5];
  int t = threadIdx.x;
  // hoisted loads
  float4 p4 = ((const float4*)(prev + b*Nn))[t];
  float4 v4 = ((const float4*)(a + b*Nn))[t];
  float v[4] = {v4.x, v4.y, v4.z, v4.w};
  float pv[4] = {p4.x, p4.y, p4.z, p4.w};
  float lmax = fmaxf(fmaxf(v[0],v[1]), fmaxf(v[2],v[3]));
  float mx = block_reduce512(lmax, red, t, true);
  float e[4]; float ps = 0.f;
  #pragma unroll
  for (int i=0;i<4;++i){ e[i] = expf(v[i]-mx); ps += e[i]; }
  float denom = block_reduce512(ps, red, t, false);
  float inv = 1.f/denom;
  #pragma unroll
  for (int i=0;i<4;++i){
    float wc = e[i]*inv;
    wg[t*4+i] = g*wc + (1.f-g)*pv[i];
  }
  __syncthreads();
  float wp[4]; float psum = 0.f;
  #pragma unroll
  for (int i=0;i<4;++i){
    int n = t*4+i;
    float wsv = s0*wg[(n+Nn-1)&(Nn-1)] + s1*wg[n] + s2*wg[(n+1)&(Nn-1)];
    wp[i] = wsv > 0.f ? __expf(gamma*__logf(wsv)) : 0.f;
    psum += wp[i];
  }
  float tot = block_reduce512(psum, red, t, false);
  float invt = 1.f/(tot + 1e-8f);
  float4 o4 = {wp[0]*invt, wp[1]*invt, wp[2]*invt, wp[3]*invt};
  ((float4*)(outw + b*Nn))[t] = o4;
}

// ---------------- Kernel 5: memory update + read_vec partials, grid (8,256)
__global__ __launch_bounds__(256) void k_memupd(
    const float* __restrict__ mem, const float* __restrict__ params,
    const float* __restrict__ w_read, const float* __restrict__ w_write,
    float* __restrict__ mem_new, float* __restrict__ prv)
{
  __shared__ __align__(16) float4 part[4][16];
  int b = blockIdx.y;
  int n0 = blockIdx.x * 256;
  int t = threadIdx.x;
  int chunk = t & 15, rr = t >> 4;
  int wave = t >> 6, lane = t & 63;
  const float* P = params + b*PSTRIDE;
  float4 e4 = ((const float4*)(P+128))[chunk];
  float4 a4 = ((const float4*)(P+192))[chunk];
  const float4* m4  = (const float4*)mem     + ((size_t)b*Nn + n0)*16;
  float4*       o4p = (float4*)mem_new       + ((size_t)b*Nn + n0)*16;
  const float*  wwb = w_write + b*Nn + n0;
  const float*  wrb = w_read  + b*Nn + n0;
  float4 acc = {0.f,0.f,0.f,0.f};
  #pragma unroll 4
  for (int p = 0; p < 16; ++p) {
    int n = p*16 + rr;
    float4 v = m4[(size_t)n*16 + chunk];
    float ww = wwb[n];
    float wr = wrb[n];
    float4 o;
    o.x = v.x*(1.f-ww*e4.x) + ww*a4.x;
    o.y = v.y*(1.f-ww*e4.y) + ww*a4.y;
    o.z = v.z*(1.f-ww*e4.z) + ww*a4.z;
    o.w = v.w*(1.f-ww*e4.w) + ww*a4.w;
    o4p[(size_t)n*16 + chunk] = o;
    acc.x += wr*v.x; acc.y += wr*v.y; acc.z += wr*v.z; acc.w += wr*v.w;
  }
  #pragma unroll
  for (int off = 16; off <= 32; off <<= 1) {
    acc.x += __shfl_xor(acc.x, off);
    acc.y += __shfl_xor(acc.y, off);
    acc.z += __shfl_xor(acc.z, off);
    acc.w += __shfl_xor(acc.w, off);
  }
  if (lane < 16) part[wave][chunk] = acc;
  __syncthreads();
  if (t < 16) {
    float4 s = part[0][t];
    #pragma unroll
    for (int w=1; w<4; ++w){ float4 q = part[w][t]; s.x+=q.x; s.y+=q.y; s.z+=q.z; s.w+=q.w; }
    *(float4*)&prv[((size_t)b*8 + blockIdx.x)*64 + t*4] = s;
  }
}

// ---------------- Kernel 6: reduce read_vec + out GEMV, grid (4,256)
__global__ __launch_bounds__(256) void k_out(
    const float* __restrict__ h_new, const float* __restrict__ prv,
    const float* __restrict__ W_o, const float* __restrict__ b_o,
    float* __restrict__ out, float* __restrict__ read_vec)
{
  __shared__ float vbuf[576];
  int b = blockIdx.y, t = threadIdx.x;
  vbuf[t]     = h_new[b*CSd + t];
  vbuf[t+256] = h_new[b*CSd + t + 256];
  if (t < 64) {
    float s = 0.f;
    #pragma unroll
    for (int i = 0; i < 8; ++i) s += prv[((size_t)b*8 + i)*64 + t];
    vbuf[512+t] = s;
    if (blockIdx.x == 0) read_vec[b*64 + t] = s;
  }
  __syncthreads();
  int wave = t >> 6, lane = t & 63;
  float vb[9];
  #pragma unroll
  for (int i = 0; i < 9; ++i) vb[i] = vbuf[i*64 + lane];
  int cbase = blockIdx.x*64 + wave*16;
  for (int jj = 0; jj < 16; ++jj) {
    int cc = cbase + jj;
    const float* w = W_o + cc*576;
    float s = 0.f;
    #pragma unroll
    for (int i = 0; i < 9; ++i) s += w[i*64 + lane] * vb[i];
    #pragma unroll
    for (int off = 32; off; off >>= 1) s += __shfl_xor(s, off);
    if (lane == 0) out[b*OUTd + cc] = s + b_o[cc];
  }
}

extern "C" void kernel_launch(void* const* d_in, const int* in_sizes, int n_in,
                              void* d_out, int out_size, void* d_ws, size_t ws_size,
                              hipStream_t stream)
{
  const float* x         = (const float*)d_in[0];
  const float* memory    = (const float*)d_in[1];
  const float* h         = (const float*)d_in[2];
  const float* c         = (const float*)d_in[3];
  const float* read_w    = (const float*)d_in[4];
  const float* write_w   = (const float*)d_in[5];
  const float* prev_read = (const float*)d_in[6];
  const float* W_ih      = (const float*)d_in[7];
  const float* W_hh      = (const float*)d_in[8];
  const float* b_ih      = (const float*)d_in[9];
  const float* b_hh      = (const float*)d_in[10];
  const float* W_r       = (const float*)d_in[11];
  const float* b_r       = (const float*)d_in[12];
  const float* W_w       = (const float*)d_in[13];
  const float* b_w       = (const float*)d_in[14];
  const float* W_o       = (const float*)d_in[15];
  const float* b_o       = (const float*)d_in[16];

  float* out      = (float*)d_out;
  float* mem_new  = out + 256*256;
  float* h_new    = mem_new + (size_t)256*2048*64;
  float* c_new    = h_new + 256*512;
  float* w_read   = c_new + 256*512;
  float* w_write  = w_read + 256*2048;
  float* read_vec = w_write + 256*2048;

  float* ws       = (float*)d_ws;
  float* params   = ws;                      // 256*PSTRIDE floats
  float* partials = params + 256*PSTRIDE;    // ZSPL * GSZ floats (8 MB)
  // aliases into dead partials space (sequential stream ordering makes this safe):
  float* a_r      = partials;                // live k_sim -> k_weights
  float* a_w      = partials + GSZ;
  float* prv      = partials + 2*GSZ;        // live k_memupd -> k_out (256*8*64)

  k_gates  <<<dim3(32,4,ZSPL), 256, 0, stream>>>(x, prev_read, h, W_ih, W_hh, partials);
  k_head   <<<256,             512, 0, stream>>>(partials, c, b_ih, b_hh, W_r, b_r, W_w, b_w,
                                                 h_new, c_new, params);
  k_sim    <<<dim3(8,256),     256, 0, stream>>>(memory, params, a_r, a_w);
  k_weights<<<dim3(256,2),     512, 0, stream>>>(a_r, a_w, read_w, write_w, params, w_read, w_write);
  k_memupd <<<dim3(8,256),     256, 0, stream>>>(memory, params, w_read, w_write, mem_new, prv);
  k_out    <<<dim3(4,256),     256, 0, stream>>>(h_new, prv, W_o, b_o, out, read_vec);
}